// Round 3
// baseline (13069.363 us; speedup 1.0000x reference)
//
#include <hip/hip_runtime.h>
#include <cstddef>

typedef _Float16 f16;
typedef _Float16 f16x8 __attribute__((ext_vector_type(8)));
typedef _Float16 f16x4 __attribute__((ext_vector_type(4)));
typedef float f32x4 __attribute__((ext_vector_type(4)));

#define T_STEPS 512
#define BATCH   64
#define DD      1024
#define NTOT    4096   // 4 gates * D, n = d*4 + g (g: 0=i,1=f,2=c,3=o)
#define NWG     64     // persistent WGs; WG j owns h cols [16j,16j+16)

// ---- workspace layout (bytes), all 4 KiB aligned ----
#define OFF_FLAGS 0ull                             // 1024 u32: flags[16*j] = step epoch of WG j
#define OFF_HBUF  4096ull                          // 2 * 64 * 1024 f16 = 262144 B
#define OFF_BIAS  (OFF_HBUF + 262144ull)           // 4096 f32
#define OFF_WHP   (OFF_BIAS + 16384ull)            // 8 MB
#define OFF_BXP   (OFF_WHP + 8388608ull)           // 8 MB
#define OFF_XW    (OFF_BXP + 8388608ull)           // 32768*4096 f16 = 256 MB

__device__ __forceinline__ float sigm(float x) { return 1.f / (1.f + __expf(-x)); }
__device__ __forceinline__ float tanh_fast(float x) {
    float e = __expf(-2.f * fabsf(x));
    float t = (1.f - e) / (1.f + e);
    return x >= 0.f ? t : -t;
}

// coherent (cross-XCD) primitives: relaxed agent-scope atomics -> sc0 sc1
__device__ __forceinline__ unsigned int load_coh_u32(const unsigned int* p) {
    return __hip_atomic_load((unsigned int*)p, __ATOMIC_RELAXED, __HIP_MEMORY_SCOPE_AGENT);
}
__device__ __forceinline__ void store_coh_u32(unsigned int* p, unsigned int v) {
    __hip_atomic_store(p, v, __ATOMIC_RELAXED, __HIP_MEMORY_SCOPE_AGENT);
}
__device__ __forceinline__ void store_coh_u64(unsigned long long* p, unsigned long long v) {
    __hip_atomic_store(p, v, __ATOMIC_RELAXED, __HIP_MEMORY_SCOPE_AGENT);
}
__device__ __forceinline__ void waitcnt_vm0() {
    asm volatile("s_waitcnt vmcnt(0)" ::: "memory");
}

// one LSTM cell for 1 output column: gates (i,f,c,o) in g4, x-contribution x0..x3
#define GATE4(g4, x0, x1, x2, x3, cvar, hvar)                        \
    {                                                                \
        float pi = (g4).x + (float)(x0);                             \
        float pf = (g4).y + (float)(x1);                             \
        float pg = (g4).z + (float)(x2);                             \
        float po = (g4).w + (float)(x3);                             \
        float iv = sigm(pi), fv = sigm(pf);                          \
        float gg = tanh_fast(pg), ov = sigm(po);                     \
        cvar = fv * cvar + iv * gg;                                  \
        hvar = ov * tanh_fast(cvar);                                 \
    }

// ---------------------------------------------------------------------------
// Prepack: weights -> f16 fragment order (B-frag for mfma_f32_16x16x32_f16:
// lane l holds B[k=S*32+(l>>4)*8+jj][n=NT*16+(l&15)] at arr[((NT*32+S)*64+l)*8+jj]).
// ---------------------------------------------------------------------------
__global__ void prepack_kernel(const float* __restrict__ Wi, const float* __restrict__ Wf,
                               const float* __restrict__ Wc, const float* __restrict__ Wo,
                               const float* __restrict__ bi, const float* __restrict__ bf,
                               const float* __restrict__ bc, const float* __restrict__ bo,
                               const float* __restrict__ c0,
                               f16* __restrict__ whp, f16* __restrict__ bxp,
                               float* __restrict__ biasp, f16* __restrict__ hbuf,
                               unsigned int* __restrict__ flags)
{
    unsigned int gid = blockIdx.x * 256u + threadIdx.x;
    if (gid < 1024u) flags[gid] = 0u;             // zero barrier flags each launch (graph replay)
    const float* Ww[4] = {Wi, Wf, Wc, Wo};
    if (gid < 8388608u) {
        unsigned int hi = (gid >= 4194304u);      // 0 -> bxp (k 0..1023), 1 -> whp (k 1024..2047)
        unsigned int e  = gid & 4194303u;
        unsigned int jj = e & 7u;
        unsigned int lidx = (e >> 3) & 63u;
        unsigned int S  = (e >> 9) & 31u;
        unsigned int NT = e >> 14;
        unsigned int n  = NT * 16u + (lidx & 15u);
        unsigned int k  = S * 32u + (lidx >> 4) * 8u + jj + (hi ? 1024u : 0u);
        unsigned int g  = n & 3u, d = n >> 2;
        float v = Ww[g][k * 1024u + d];
        (hi ? whp : bxp)[e] = (f16)v;
    } else if (gid < 8392704u) {                  // bias: 4096
        unsigned int n = gid - 8388608u;
        const float* Bb[4] = {bi, bf, bc, bo};
        biasp[n] = Bb[n & 3u][n >> 2];
    } else if (gid < 8458240u) {                  // hbuf[0][b][d] = tanh(c0[d]) : 65536
        unsigned int e2 = gid - 8392704u;
        hbuf[e2] = (f16)tanh_fast(c0[e2 & 1023u]);
    }
}

// ---------------------------------------------------------------------------
// Phase 1: xw[m][n] = batch[m][:1024] @ Wx[:, n] + bias[n]   (f16 out)
// ---------------------------------------------------------------------------
__global__ __launch_bounds__(256) void gemm_x_kernel(
    const float* __restrict__ A, const f16* __restrict__ Bp,
    const float* __restrict__ biasp, f16* __restrict__ xw)
{
    const int tid = threadIdx.x;
    const int w = tid >> 6, l = tid & 63;
    const int lr = l & 15, lq = l >> 4;
    const int n0 = blockIdx.x * 128;
    const int m0 = blockIdx.y * 128;

    f32x4 acc[2][8];
#pragma unroll
    for (int mt = 0; mt < 2; mt++)
#pragma unroll
        for (int nt = 0; nt < 8; nt++) acc[mt][nt] = (f32x4){0.f, 0.f, 0.f, 0.f};

    const float* a0 = A + (size_t)(m0 + 32 * w + lr) * 1024 + lq * 8;
    const f16x8* bp = (const f16x8*)Bp + (size_t)(n0 >> 4) * (32 * 64) + l;

#pragma unroll 2
    for (int s = 0; s < 32; s++) {
        f16x8 af[2];
#pragma unroll
        for (int mt = 0; mt < 2; mt++) {
            const float* ap = a0 + mt * (16 * 1024) + 32 * s;
            float4 v0 = *(const float4*)ap;
            float4 v1 = *(const float4*)(ap + 4);
            f16x8 tt;
            tt[0] = (f16)v0.x; tt[1] = (f16)v0.y; tt[2] = (f16)v0.z; tt[3] = (f16)v0.w;
            tt[4] = (f16)v1.x; tt[5] = (f16)v1.y; tt[6] = (f16)v1.z; tt[7] = (f16)v1.w;
            af[mt] = tt;
        }
#pragma unroll
        for (int nt = 0; nt < 8; nt++) {
            f16x8 bfr = bp[(size_t)(nt * 32 + s) * 64];
            acc[0][nt] = __builtin_amdgcn_mfma_f32_16x16x32_f16(af[0], bfr, acc[0][nt], 0, 0, 0);
            acc[1][nt] = __builtin_amdgcn_mfma_f32_16x16x32_f16(af[1], bfr, acc[1][nt], 0, 0, 0);
        }
    }
#pragma unroll
    for (int nt = 0; nt < 8; nt++) {
        int n = n0 + nt * 16 + lr;
        float bias = biasp[n];
#pragma unroll
        for (int mt = 0; mt < 2; mt++) {
#pragma unroll
            for (int r = 0; r < 4; r++) {
                int m = m0 + 32 * w + mt * 16 + lq * 4 + r;
                xw[(size_t)m * NTOT + n] = (f16)(acc[mt][nt][r] + bias);
            }
        }
    }
}

// ---------------------------------------------------------------------------
// Phase 2: persistent recurrent kernel. 64 WGs x 1024 thr (16 waves). WG j
// owns h cols [16j,16j+16) = gate cols [64j,64j+64). Weights: 128 KB dynamic
// LDS. Wave w = (bt=w>>2, nt=w&3) computes D-tile rows [16bt,16bt+16) x gate
// cols [16nt,16nt+16) over k=1024 (32 MFMAs). Activation: tid<256, thread
// (b=tid>>2,q=tid&3) owns d = 16j+4q..+4; h stored as ONE coherent u64.
// Barrier: single-level, RMW-free. tid0 coherent-stores flags[16j]=t+1;
// wave 0 polls all 64 flags in parallel (lane l watches WG l) via __all.
// Then one agent-acquire fence; h loads are plain cached loads.
// ---------------------------------------------------------------------------
__global__ __launch_bounds__(1024, 1) void lstm_persist_kernel(
    const f16* __restrict__ xw, const f16* __restrict__ whp,
    const int* __restrict__ lengths, const float* __restrict__ c0,
    float* __restrict__ out, f16* hbuf, unsigned int* flags)
{
    extern __shared__ __align__(16) char smem[];
    f16*   wlds    = (f16*)smem;                  // 128 KB weight fragments
    float* pre_lds = (float*)(smem + 131072);     // 64 x 68 f32 (padded stride)

    const int j = blockIdx.x;
    const int tid = threadIdx.x;
    const int wv = tid >> 6, l = tid & 63;
    const int lr = l & 15, lq = l >> 4;
    const int bt = wv >> 2, nt = wv & 3;

    // stage this WG's 128 KB of recurrent-weight fragments (4 n-tiles)
    {
        const f16x8* wp = (const f16x8*)whp + (size_t)j * 8192;
        f16x8* wl0 = (f16x8*)wlds;
        for (int i = tid; i < 8192; i += 1024) wl0[i] = wp[i];
    }
    __syncthreads();

    const int rowA = 16 * bt + lr;
    const int koff = lq * 8;
    const f16x8* wl = (const f16x8*)wlds + nt * 2048 + l;   // + s*64 per slice

    // activation mapping (tid < 256): thread (b,q) owns d = 16j+4q .. +4
    const int b = tid >> 2, q = tid & 3;
    float cA = 0.f, cB = 0.f, cC = 0.f, cD = 0.f;
    int len = 0;
    const f16* xwbase = nullptr;
    f16x8 xg0 = (f16x8)0, xg1 = (f16x8)0;
    if (tid < 256) {
        float4 ci = *(const float4*)&c0[16 * j + 4 * q];
        cA = ci.x; cB = ci.y; cC = ci.z; cD = ci.w;
        len = lengths[b];
        xwbase = xw + (size_t)b * NTOT + 64 * j + 16 * q;   // 16 gate cols window
        xg0 = *(const f16x8*)xwbase;                        // step-0 x-contribution
        xg1 = *(const f16x8*)(xwbase + 8);
    }

    for (int t = 0; t < T_STEPS; t++) {
        const int p = t & 1;
        const f16* hb = hbuf + (size_t)p * (BATCH * DD);
        const f16x8* ap = (const f16x8*)(hb + (size_t)rowA * DD + koff);  // + s*4 per slice

        // prefetch next step's xw slice (read-only, fence-immune)
        f16x8 xg0n = xg0, xg1n = xg1;
        if (tid < 256 && t + 1 < T_STEPS) {
            const f16* nx = xwbase + (size_t)(t + 1) * (BATCH * NTOT);
            xg0n = *(const f16x8*)nx;
            xg1n = *(const f16x8*)(nx + 8);
        }

        f32x4 acc0 = {0.f, 0.f, 0.f, 0.f}, acc1 = {0.f, 0.f, 0.f, 0.f};
#pragma unroll
        for (int s = 0; s < 32; s += 2) {
            f16x8 a0 = ap[4 * s];
            f16x8 a1 = ap[4 * (s + 1)];
            f16x8 w0 = wl[64 * s];
            f16x8 w1 = wl[64 * (s + 1)];
            acc0 = __builtin_amdgcn_mfma_f32_16x16x32_f16(a0, w0, acc0, 0, 0, 0);
            acc1 = __builtin_amdgcn_mfma_f32_16x16x32_f16(a1, w1, acc1, 0, 0, 0);
        }
        f32x4 pre = acc0 + acc1;
        // D layout: row = 16bt + lq*4 + r (batch), col = 16nt + lr (gate col local)
#pragma unroll
        for (int r = 0; r < 4; r++)
            pre_lds[(16 * bt + lq * 4 + r) * 68 + 16 * nt + lr] = pre[r];
        __syncthreads();

        float4 oh = (float4){0.f, 0.f, 0.f, 0.f};
        if (tid < 256) {
            const float* pr = &pre_lds[b * 68 + 16 * q];
            float4 g0 = *(const float4*)(pr + 0);
            float4 g1 = *(const float4*)(pr + 4);
            float4 g2 = *(const float4*)(pr + 8);
            float4 g3 = *(const float4*)(pr + 12);
            float h0, h1, h2, h3;
            GATE4(g0, xg0[0], xg0[1], xg0[2], xg0[3], cA, h0);
            GATE4(g1, xg0[4], xg0[5], xg0[6], xg0[7], cB, h1);
            GATE4(g2, xg1[0], xg1[1], xg1[2], xg1[3], cC, h2);
            GATE4(g3, xg1[4], xg1[5], xg1[6], xg1[7], cD, h3);
            if (t >= len) { h0 = 0.f; h1 = 0.f; h2 = 0.f; h3 = 0.f; }  // ref: mask carried+emitted
            oh = (float4){h0, h1, h2, h3};
            if (t + 1 < T_STEPS) {
                f16x4 hv;
                hv[0] = (f16)h0; hv[1] = (f16)h1; hv[2] = (f16)h2; hv[3] = (f16)h3;
                store_coh_u64((unsigned long long*)(hbuf + (size_t)(p ^ 1) * (BATCH * DD)
                                                    + (size_t)b * DD + 16 * j + 4 * q),
                              __builtin_bit_cast(unsigned long long, hv));
            }
        }

        if (t + 1 < T_STEPS) {
            waitcnt_vm0();                    // h stores acked at coherency point
            __syncthreads();                  // whole WG done storing
            if (tid == 0) store_coh_u32(flags + 16 * j, (unsigned int)(t + 1));
            // out store off the critical path (overlaps the poll)
            if (tid < 256)
                *(float4*)(out + (size_t)t * (BATCH * DD) + (size_t)b * DD + 16 * j + 4 * q) = oh;
            if (wv == 0) {                    // wave-parallel poll: lane l watches WG l
                const unsigned int want = (unsigned int)(t + 1);
                while (!__all(load_coh_u32(flags + 16 * l) >= want))
                    __builtin_amdgcn_s_sleep(1);
            }
            __syncthreads();                  // all waves ordered after observation
            // invalidate stale L1/L2 h lines before next step's cached loads
            __builtin_amdgcn_fence(__ATOMIC_ACQUIRE, "agent");
            asm volatile("" ::: "memory");
        } else {
            if (tid < 256)
                *(float4*)(out + (size_t)t * (BATCH * DD) + (size_t)b * DD + 16 * j + 4 * q) = oh;
        }
        xg0 = xg0n; xg1 = xg1n;
    }
}

// ---------------------------------------------------------------------------
extern "C" void kernel_launch(void* const* d_in, const int* in_sizes, int n_in,
                              void* d_out, int out_size, void* d_ws, size_t ws_size,
                              hipStream_t stream) {
    const float* batch   = (const float*)d_in[0];
    const int*   lengths = (const int*)d_in[1];
    const float* c0      = (const float*)d_in[2];
    const float* Wi = (const float*)d_in[3];
    const float* bi = (const float*)d_in[4];
    const float* Wf = (const float*)d_in[5];
    const float* bf = (const float*)d_in[6];
    const float* Wc = (const float*)d_in[7];
    const float* bc = (const float*)d_in[8];
    const float* Wo = (const float*)d_in[9];
    const float* bo = (const float*)d_in[10];
    float* out = (float*)d_out;

    char* ws = (char*)d_ws;
    unsigned int* flags = (unsigned int*)(ws + OFF_FLAGS);
    f16*   hbuf  = (f16*)(ws + OFF_HBUF);
    float* biasp = (float*)(ws + OFF_BIAS);
    f16*   whp   = (f16*)(ws + OFF_WHP);
    f16*   bxp   = (f16*)(ws + OFF_BXP);
    f16*   xw    = (f16*)(ws + OFF_XW);

    prepack_kernel<<<33040, 256, 0, stream>>>(Wi, Wf, Wc, Wo, bi, bf, bc, bo, c0,
                                              whp, bxp, biasp, hbuf, flags);
    gemm_x_kernel<<<dim3(32, 256), 256, 0, stream>>>(batch, bxp, biasp, xw);
    // dynamic LDS: 128 KB weights + 64*68*4 B pre = 148480 B (<160 KB/CU)
    lstm_persist_kernel<<<NWG, 1024, 148480, stream>>>(xw, whp, lengths, c0, out, hbuf, flags);
}

// Round 5
// 5744.552 us; speedup vs baseline: 2.2751x; 2.2751x over previous
//
#include <hip/hip_runtime.h>
#include <cstddef>

typedef _Float16 f16;
typedef _Float16 f16x8 __attribute__((ext_vector_type(8)));
typedef _Float16 f16x4 __attribute__((ext_vector_type(4)));
typedef float f32x4 __attribute__((ext_vector_type(4)));

#define T_STEPS 512
#define BATCH   64
#define DD      1024
#define NTOT    4096   // 4 gates * D, n = d*4 + g (g: 0=i,1=f,2=c,3=o)

// ---- workspace layout (bytes) ----
// Common prefix (proven <= 273 MB budget):
#define OFF_FLAGS 0ull                             // 1024 u32 barrier counters
#define OFF_HBUF  4096ull                          // 2 * 64 * 1024 f16 = 262144 B (fence variant)
#define OFF_BIAS  (OFF_HBUF + 262144ull)           // 4096 f32
#define OFF_WHP   (OFF_BIAS + 16384ull)            // 8 MB
#define OFF_BXP   (OFF_WHP + 8388608ull)           // 8 MB
#define OFF_XW    (OFF_BXP + 8388608ull)           // 32768*4096 f16 = 256 MB
#define XW_END    (OFF_XW + 268435456ull)          // ~272.3 MB
// Optional h ring (virgin-address scheme), only if workspace allows:
#define RSTRIDE_B 139264ull                        // 136 KB per slot (page multiple)
#define RSTRIDE_H 69632ull                         // in f16 units
#define OFF_RING  XW_END                           // 512 slots * 136 KB = 68 MB
#define RING_END  (OFF_RING + 512ull * RSTRIDE_B)  // ~340.3 MB

// barrier state (u32 indices): flags[g*16], g=0..15 group counters; flags[256] super

__device__ __forceinline__ float sigm(float x) { return 1.f / (1.f + __expf(-x)); }
__device__ __forceinline__ float tanh_fast(float x) {
    float e = __expf(-2.f * fabsf(x));
    float t = (1.f - e) / (1.f + e);
    return x >= 0.f ? t : -t;
}

// coherent (cross-XCD) primitives: relaxed agent-scope atomics -> sc0 sc1
__device__ __forceinline__ unsigned int load_coh_u32(const unsigned int* p) {
    return __hip_atomic_load((unsigned int*)p, __ATOMIC_RELAXED, __HIP_MEMORY_SCOPE_AGENT);
}
__device__ __forceinline__ void store_coh_u64(unsigned long long* p, unsigned long long v) {
    __hip_atomic_store(p, v, __ATOMIC_RELAXED, __HIP_MEMORY_SCOPE_AGENT);
}
__device__ __forceinline__ unsigned int fetch_add_coh(unsigned int* p, unsigned int v) {
    return __hip_atomic_fetch_add(p, v, __ATOMIC_RELAXED, __HIP_MEMORY_SCOPE_AGENT);
}
__device__ __forceinline__ void waitcnt_vm0() {
    asm volatile("s_waitcnt vmcnt(0)" ::: "memory");
}

// one LSTM cell for 1 output column: gates (i,f,c,o) in g4, x-contribution x0..x3
#define GATE4(g4, x0, x1, x2, x3, cvar, hvar)                        \
    {                                                                \
        float pi = (g4).x + (float)(x0);                             \
        float pf = (g4).y + (float)(x1);                             \
        float pg = (g4).z + (float)(x2);                             \
        float po = (g4).w + (float)(x3);                             \
        float iv = sigm(pi), fv = sigm(pf);                          \
        float gg = tanh_fast(pg), ov = sigm(po);                     \
        cvar = fv * cvar + iv * gg;                                  \
        hvar = ov * tanh_fast(cvar);                                 \
    }

// ---------------------------------------------------------------------------
// Prepack: weights -> f16 fragment order (B-frag for mfma_f32_16x16x32_f16:
// lane l holds B[k=S*32+(l>>4)*8+jj][n=NT*16+(l&15)] at arr[((NT*32+S)*64+l)*8+jj]).
// h0dst: destination for h_0 = tanh(c0) (hbuf slot 0 OR ring slot 0).
// ---------------------------------------------------------------------------
__global__ void prepack_kernel(const float* __restrict__ Wi, const float* __restrict__ Wf,
                               const float* __restrict__ Wc, const float* __restrict__ Wo,
                               const float* __restrict__ bi, const float* __restrict__ bf,
                               const float* __restrict__ bc, const float* __restrict__ bo,
                               const float* __restrict__ c0,
                               f16* __restrict__ whp, f16* __restrict__ bxp,
                               float* __restrict__ biasp, f16* __restrict__ h0dst,
                               unsigned int* __restrict__ flags)
{
    unsigned int gid = blockIdx.x * 256u + threadIdx.x;
    if (gid < 1024u) flags[gid] = 0u;             // zero barrier counters each launch (graph replay)
    const float* Ww[4] = {Wi, Wf, Wc, Wo};
    if (gid < 8388608u) {
        unsigned int hi = (gid >= 4194304u);      // 0 -> bxp (k 0..1023), 1 -> whp (k 1024..2047)
        unsigned int e  = gid & 4194303u;
        unsigned int jj = e & 7u;
        unsigned int lidx = (e >> 3) & 63u;
        unsigned int S  = (e >> 9) & 31u;
        unsigned int NT = e >> 14;
        unsigned int n  = NT * 16u + (lidx & 15u);
        unsigned int k  = S * 32u + (lidx >> 4) * 8u + jj + (hi ? 1024u : 0u);
        unsigned int g  = n & 3u, d = n >> 2;
        float v = Ww[g][k * 1024u + d];
        (hi ? whp : bxp)[e] = (f16)v;
    } else if (gid < 8392704u) {                  // bias: 4096
        unsigned int n = gid - 8388608u;
        const float* Bb[4] = {bi, bf, bc, bo};
        biasp[n] = Bb[n & 3u][n >> 2];
    } else if (gid < 8458240u) {                  // h_0[b][d] = tanh(c0[d]) : 65536
        unsigned int e2 = gid - 8392704u;
        h0dst[e2] = (f16)tanh_fast(c0[e2 & 1023u]);
    }
}

// ---------------------------------------------------------------------------
// Phase 1: xw[m][n] = batch[m][:1024] @ Wx[:, n] + bias[n]   (f16 out)
// ---------------------------------------------------------------------------
__global__ __launch_bounds__(256) void gemm_x_kernel(
    const float* __restrict__ A, const f16* __restrict__ Bp,
    const float* __restrict__ biasp, f16* __restrict__ xw)
{
    const int tid = threadIdx.x;
    const int w = tid >> 6, l = tid & 63;
    const int lr = l & 15, lq = l >> 4;
    const int n0 = blockIdx.x * 128;
    const int m0 = blockIdx.y * 128;

    f32x4 acc[2][8];
#pragma unroll
    for (int mt = 0; mt < 2; mt++)
#pragma unroll
        for (int nt = 0; nt < 8; nt++) acc[mt][nt] = (f32x4){0.f, 0.f, 0.f, 0.f};

    const float* a0 = A + (size_t)(m0 + 32 * w + lr) * 1024 + lq * 8;
    const f16x8* bp = (const f16x8*)Bp + (size_t)(n0 >> 4) * (32 * 64) + l;

#pragma unroll 2
    for (int s = 0; s < 32; s++) {
        f16x8 af[2];
#pragma unroll
        for (int mt = 0; mt < 2; mt++) {
            const float* ap = a0 + mt * (16 * 1024) + 32 * s;
            float4 v0 = *(const float4*)ap;
            float4 v1 = *(const float4*)(ap + 4);
            f16x8 tt;
            tt[0] = (f16)v0.x; tt[1] = (f16)v0.y; tt[2] = (f16)v0.z; tt[3] = (f16)v0.w;
            tt[4] = (f16)v1.x; tt[5] = (f16)v1.y; tt[6] = (f16)v1.z; tt[7] = (f16)v1.w;
            af[mt] = tt;
        }
#pragma unroll
        for (int nt = 0; nt < 8; nt++) {
            f16x8 bfr = bp[(size_t)(nt * 32 + s) * 64];
            acc[0][nt] = __builtin_amdgcn_mfma_f32_16x16x32_f16(af[0], bfr, acc[0][nt], 0, 0, 0);
            acc[1][nt] = __builtin_amdgcn_mfma_f32_16x16x32_f16(af[1], bfr, acc[1][nt], 0, 0, 0);
        }
    }
#pragma unroll
    for (int nt = 0; nt < 8; nt++) {
        int n = n0 + nt * 16 + lr;
        float bias = biasp[n];
#pragma unroll
        for (int mt = 0; mt < 2; mt++) {
#pragma unroll
            for (int r = 0; r < 4; r++) {
                int m = m0 + 32 * w + mt * 16 + lq * 4 + r;
                xw[(size_t)m * NTOT + n] = (f16)(acc[mt][nt][r] + bias);
            }
        }
    }
}

// ---------------------------------------------------------------------------
// Phase-2 shared body. RING=1: h into per-step virgin ring slot (no fence).
// RING=0: h double-buffer + agent-acquire fence per step (proven round-2).
// 256 WGs x 256 thr; WG j owns gate cols [16j,16j+16) = h cols [4j,4j+4).
// Activation: tid<64, thread b computes 4 h cols, ONE coherent u64 h store.
// Barrier: tree (group fetch_add + super), tid0-only poll.
// ---------------------------------------------------------------------------
template <int RING>
__device__ __forceinline__ void lstm_persist_body(
    const f16* __restrict__ xw, const f16* __restrict__ whp,
    const int* __restrict__ lengths, const float* __restrict__ c0,
    float* __restrict__ out, f16* hmem, unsigned int* flags)
{
    const int j = blockIdx.x;
    const int tid = threadIdx.x;
    const int w = tid >> 6, l = tid & 63;
    const int lr = l & 15, lq = l >> 4;

    __shared__ f16 wlds[32 * 64 * 8];     // 32 KB: weight fragments
    __shared__ float pre_lds[64 * 20];    // 5 KB: pre-activation, stride 20 (pad)

    // stage this WG's recurrent-weight fragments into LDS (2048 x 16B)
    {
        const f16x8* wp = (const f16x8*)whp + (size_t)j * 2048;
        f16x8* wl0 = (f16x8*)wlds;
        for (int i = tid; i < 2048; i += 256) wl0[i] = wp[i];
    }
    __syncthreads();

    const int rowA = 16 * w + lr;
    const int koff = lq * 8;
    const f16x8* wl = (const f16x8*)wlds + l;   // + s*64 per slice

    unsigned int* gcnt   = flags + ((unsigned int)j >> 4) * 16u;  // own 64B line
    unsigned int* superp = flags + 256u;                          // own line

    // activation mapping (tid < 64): thread b owns h cols [4j,4j+4)
    const int b = tid;
    float cA = 0.f, cB = 0.f, cC = 0.f, cD = 0.f;
    int len = 0;
    const f16* xwbase = nullptr;
    f16x8 xg0 = (f16x8)0, xg1 = (f16x8)0;
    if (tid < 64) {
        float4 ci = *(const float4*)&c0[4 * j];
        cA = ci.x; cB = ci.y; cC = ci.z; cD = ci.w;
        len = lengths[b];
        xwbase = xw + (size_t)b * NTOT + 16 * j;            // 16 gate cols window
        xg0 = *(const f16x8*)xwbase;                        // step-0 x-contribution
        xg1 = *(const f16x8*)(xwbase + 8);
    }

    for (int t = 0; t < T_STEPS; t++) {
        // read slot: ring slot t (virgin) or double-buffer slot t&1
        const f16* hb = RING ? (hmem + (size_t)t * RSTRIDE_H)
                             : (hmem + (size_t)(t & 1) * (BATCH * DD));
        const f16x8* ap = (const f16x8*)(hb + (size_t)rowA * DD + koff);  // + s*4 per slice

        // prefetch next step's xw slice (read-only phase-1 data)
        f16x8 xg0n = xg0, xg1n = xg1;
        if (tid < 64 && t + 1 < T_STEPS) {
            const f16* nx = xwbase + (size_t)(t + 1) * (BATCH * NTOT);
            xg0n = *(const f16x8*)nx;
            xg1n = *(const f16x8*)(nx + 8);
        }

        f32x4 acc0 = {0.f, 0.f, 0.f, 0.f}, acc1 = {0.f, 0.f, 0.f, 0.f};
#pragma unroll
        for (int s = 0; s < 32; s += 2) {
            f16x8 a0 = ap[4 * s];
            f16x8 a1 = ap[4 * (s + 1)];
            f16x8 w0 = wl[64 * s];
            f16x8 w1 = wl[64 * (s + 1)];
            acc0 = __builtin_amdgcn_mfma_f32_16x16x32_f16(a0, w0, acc0, 0, 0, 0);
            acc1 = __builtin_amdgcn_mfma_f32_16x16x32_f16(a1, w1, acc1, 0, 0, 0);
        }
        f32x4 pre = acc0 + acc1;
        // D layout: row = 16w + lq*4 + r (batch), col = lr (gate col local)
#pragma unroll
        for (int r = 0; r < 4; r++)
            pre_lds[(16 * w + lq * 4 + r) * 20 + lr] = pre[r];
        __syncthreads();

        float4 oh = (float4){0.f, 0.f, 0.f, 0.f};
        if (tid < 64) {
            const float* pr = &pre_lds[b * 20];
            float4 g0 = *(const float4*)(pr + 0);
            float4 g1 = *(const float4*)(pr + 4);
            float4 g2 = *(const float4*)(pr + 8);
            float4 g3 = *(const float4*)(pr + 12);
            float h0, h1, h2, h3;
            GATE4(g0, xg0[0], xg0[1], xg0[2], xg0[3], cA, h0);
            GATE4(g1, xg0[4], xg0[5], xg0[6], xg0[7], cB, h1);
            GATE4(g2, xg1[0], xg1[1], xg1[2], xg1[3], cC, h2);
            GATE4(g3, xg1[4], xg1[5], xg1[6], xg1[7], cD, h3);
            if (t >= len) { h0 = 0.f; h1 = 0.f; h2 = 0.f; h3 = 0.f; }  // ref: mask carried+emitted
            oh = (float4){h0, h1, h2, h3};
            if (t + 1 < T_STEPS) {
                f16x4 hv;
                hv[0] = (f16)h0; hv[1] = (f16)h1; hv[2] = (f16)h2; hv[3] = (f16)h3;
                f16* dst = RING ? (hmem + (size_t)(t + 1) * RSTRIDE_H)
                                : (hmem + (size_t)((t + 1) & 1) * (BATCH * DD));
                store_coh_u64((unsigned long long*)(dst + (size_t)b * DD + 4 * j),
                              __builtin_bit_cast(unsigned long long, hv));
            }
        }

        if (t + 1 < T_STEPS) {
            waitcnt_vm0();                    // h stores acked at coherency point
            __syncthreads();                  // whole WG done storing
            if (tid == 0) {
                const unsigned int want = 16u * (unsigned int)(t + 1);
                unsigned int old = fetch_add_coh(gcnt, 1u);
                if (old == want - 1u)         // last arriver of this group
                    (void)fetch_add_coh(superp, 1u);
            }
            // out store off the critical path (overlaps barrier)
            if (tid < 64)
                *(float4*)(out + (size_t)t * (BATCH * DD) + (size_t)b * DD + 4 * j) = oh;
            if (tid == 0) {
                const unsigned int want = 16u * (unsigned int)(t + 1);
                while (load_coh_u32(superp) < want)
                    __builtin_amdgcn_s_sleep(1);
            }
            __syncthreads();                  // all threads ordered after observation
            if (!RING) {
                // invalidate stale L1/L2 h lines before next step's cached loads
                __builtin_amdgcn_fence(__ATOMIC_ACQUIRE, "agent");
            }
            // RING: next step reads a virgin slot (cannot be stale-cached) -> no fence
            asm volatile("" ::: "memory");
        } else {
            if (tid < 64)
                *(float4*)(out + (size_t)t * (BATCH * DD) + (size_t)b * DD + 4 * j) = oh;
        }
        xg0 = xg0n; xg1 = xg1n;
    }
}

__global__ __launch_bounds__(256, 1) void lstm_persist_ring(
    const f16* __restrict__ xw, const f16* __restrict__ whp,
    const int* __restrict__ lengths, const float* __restrict__ c0,
    float* __restrict__ out, f16* ring, unsigned int* flags)
{
    lstm_persist_body<1>(xw, whp, lengths, c0, out, ring, flags);
}

__global__ __launch_bounds__(256, 1) void lstm_persist_fence(
    const f16* __restrict__ xw, const f16* __restrict__ whp,
    const int* __restrict__ lengths, const float* __restrict__ c0,
    float* __restrict__ out, f16* hbuf, unsigned int* flags)
{
    lstm_persist_body<0>(xw, whp, lengths, c0, out, hbuf, flags);
}

// ---------------------------------------------------------------------------
extern "C" void kernel_launch(void* const* d_in, const int* in_sizes, int n_in,
                              void* d_out, int out_size, void* d_ws, size_t ws_size,
                              hipStream_t stream) {
    const float* batch   = (const float*)d_in[0];
    const int*   lengths = (const int*)d_in[1];
    const float* c0      = (const float*)d_in[2];
    const float* Wi = (const float*)d_in[3];
    const float* bi = (const float*)d_in[4];
    const float* Wf = (const float*)d_in[5];
    const float* bf = (const float*)d_in[6];
    const float* Wc = (const float*)d_in[7];
    const float* bc = (const float*)d_in[8];
    const float* Wo = (const float*)d_in[9];
    const float* bo = (const float*)d_in[10];
    float* out = (float*)d_out;

    char* ws = (char*)d_ws;
    unsigned int* flags = (unsigned int*)(ws + OFF_FLAGS);
    f16*   hbuf  = (f16*)(ws + OFF_HBUF);
    float* biasp = (float*)(ws + OFF_BIAS);
    f16*   whp   = (f16*)(ws + OFF_WHP);
    f16*   bxp   = (f16*)(ws + OFF_BXP);
    f16*   xw    = (f16*)(ws + OFF_XW);
    f16*   ring  = (f16*)(ws + OFF_RING);

    const bool use_ring = (ws_size >= RING_END);   // ring needs ~340 MB workspace
    f16* h0dst = use_ring ? ring : hbuf;

    prepack_kernel<<<33040, 256, 0, stream>>>(Wi, Wf, Wc, Wo, bi, bf, bc, bo, c0,
                                              whp, bxp, biasp, h0dst, flags);
    gemm_x_kernel<<<dim3(32, 256), 256, 0, stream>>>(batch, bxp, biasp, xw);
    if (use_ring)
        lstm_persist_ring<<<256, 256, 0, stream>>>(xw, whp, lengths, c0, out, ring, flags);
    else
        lstm_persist_fence<<<256, 256, 0, stream>>>(xw, whp, lengths, c0, out, hbuf, flags);
}

// Round 6
// 4125.373 us; speedup vs baseline: 3.1680x; 1.3925x over previous
//
#include <hip/hip_runtime.h>
#include <cstddef>

typedef _Float16 f16;
typedef _Float16 f16x8 __attribute__((ext_vector_type(8)));
typedef _Float16 f16x4 __attribute__((ext_vector_type(4)));
typedef float f32x4 __attribute__((ext_vector_type(4)));

#define T_STEPS 512
#define BATCH   64
#define DD      1024
#define NTOT    4096   // 4 gates * D, n = d*4 + g (g: 0=i,1=f,2=c,3=o)

// Decomposition: 4 independent groups of 16 batch rows (batch elements are
// independent LSTM chains). Group g = blockIdx&3, member j2 = blockIdx>>2
// (0..63). WG (g,j2) owns gate cols [64*j2, 64*j2+64) = h cols [16*j2,+16)
// for batch rows [16g, 16g+16). Sync is per-group: 64 flags, no RMW.

// h ring: one fresh slot per step -> plain cached reads can never hit a stale
// line -> NO acquire fence / L2 invalidate anywhere. Slot = 4 group slabs of
// 16x1024 f16 (32 KB); slab-major == linear [b][d] since rows are contiguous.
#define RSTRIDE_B 139264ull                        // 136 KB per slot (page multiple)
#define RSTRIDE_H 69632ull                         // in f16 units
#define GSLAB_H   16384ull                         // group slab: 16*1024 f16

// ---- workspace layout (bytes); total kept < proven 356.8 MB budget ----
#define OFF_FLAGS 0ull                             // 4096 u32 = 16 KB flag lines
#define OFF_BIAS  16384ull                         // 4096 f32
#define OFF_WHP   32768ull                         // 8 MB
#define OFF_BXP   (OFF_WHP + 8388608ull)           // 8 MB
#define OFF_XW    (OFF_BXP + 8388608ull)           // 32768*4096 f16 = 256 MB
#define XW_END    (OFF_XW + 268435456ull)
#define OFF_RING  XW_END                           // 512 slots * 136 KB = 68 MB
#define RING_END  (OFF_RING + 512ull * RSTRIDE_B)  // ~356.5 MB total

// flags (u32 indices): group g, member j2 -> flags[g*1024 + j2*16] (own 64B line)

__device__ __forceinline__ float sigm(float x) { return 1.f / (1.f + __expf(-x)); }
__device__ __forceinline__ float tanh_fast(float x) {
    float e = __expf(-2.f * fabsf(x));
    float t = (1.f - e) / (1.f + e);
    return x >= 0.f ? t : -t;
}

// coherent (cross-XCD) primitives: relaxed agent-scope atomics -> sc0 sc1
__device__ __forceinline__ unsigned int load_coh_u32(const unsigned int* p) {
    return __hip_atomic_load((unsigned int*)p, __ATOMIC_RELAXED, __HIP_MEMORY_SCOPE_AGENT);
}
__device__ __forceinline__ void store_coh_u32(unsigned int* p, unsigned int v) {
    __hip_atomic_store(p, v, __ATOMIC_RELAXED, __HIP_MEMORY_SCOPE_AGENT);
}
__device__ __forceinline__ void store_coh_u64(unsigned long long* p, unsigned long long v) {
    __hip_atomic_store(p, v, __ATOMIC_RELAXED, __HIP_MEMORY_SCOPE_AGENT);
}
__device__ __forceinline__ void waitcnt_vm0() {
    asm volatile("s_waitcnt vmcnt(0)" ::: "memory");
}

// one LSTM cell for 1 output column: gates (i,f,c,o) in g4, x-contribution x0..x3
#define GATE4(g4, x0, x1, x2, x3, cvar, hvar)                        \
    {                                                                \
        float pi = (g4).x + (float)(x0);                             \
        float pf = (g4).y + (float)(x1);                             \
        float pg = (g4).z + (float)(x2);                             \
        float po = (g4).w + (float)(x3);                             \
        float iv = sigm(pi), fv = sigm(pf);                          \
        float gg = tanh_fast(pg), ov = sigm(po);                     \
        cvar = fv * cvar + iv * gg;                                  \
        hvar = ov * tanh_fast(cvar);                                 \
    }

// ---------------------------------------------------------------------------
// Prepack: weights -> f16 fragment order (B-frag for mfma_f32_16x16x32_f16:
// lane l holds B[k=S*32+(l>>4)*8+jj][n=NT*16+(l&15)] at arr[((NT*32+S)*64+l)*8+jj]).
// ring0: h_0 = tanh(c0) broadcast; linear [b][d] == grouped slab layout.
// ---------------------------------------------------------------------------
__global__ void prepack_kernel(const float* __restrict__ Wi, const float* __restrict__ Wf,
                               const float* __restrict__ Wc, const float* __restrict__ Wo,
                               const float* __restrict__ bi, const float* __restrict__ bf,
                               const float* __restrict__ bc, const float* __restrict__ bo,
                               const float* __restrict__ c0,
                               f16* __restrict__ whp, f16* __restrict__ bxp,
                               float* __restrict__ biasp, f16* __restrict__ ring0,
                               unsigned int* __restrict__ flags)
{
    unsigned int gid = blockIdx.x * 256u + threadIdx.x;
    if (gid < 4096u) flags[gid] = 0u;             // zero flag region each launch (graph replay)
    const float* Ww[4] = {Wi, Wf, Wc, Wo};
    if (gid < 8388608u) {
        unsigned int hi = (gid >= 4194304u);      // 0 -> bxp (k 0..1023), 1 -> whp (k 1024..2047)
        unsigned int e  = gid & 4194303u;
        unsigned int jj = e & 7u;
        unsigned int lidx = (e >> 3) & 63u;
        unsigned int S  = (e >> 9) & 31u;
        unsigned int NT = e >> 14;
        unsigned int n  = NT * 16u + (lidx & 15u);
        unsigned int k  = S * 32u + (lidx >> 4) * 8u + jj + (hi ? 1024u : 0u);
        unsigned int g  = n & 3u, d = n >> 2;
        float v = Ww[g][k * 1024u + d];
        (hi ? whp : bxp)[e] = (f16)v;
    } else if (gid < 8392704u) {                  // bias: 4096
        unsigned int n = gid - 8388608u;
        const float* Bb[4] = {bi, bf, bc, bo};
        biasp[n] = Bb[n & 3u][n >> 2];
    } else if (gid < 8458240u) {                  // h_0[b][d] = tanh(c0[d]) : 65536
        unsigned int e2 = gid - 8392704u;
        ring0[e2] = (f16)tanh_fast(c0[e2 & 1023u]);
    }
}

// ---------------------------------------------------------------------------
// Phase 1: xw[m][n] = batch[m][:1024] @ Wx[:, n] + bias[n]   (f16 out)
// ---------------------------------------------------------------------------
__global__ __launch_bounds__(256) void gemm_x_kernel(
    const float* __restrict__ A, const f16* __restrict__ Bp,
    const float* __restrict__ biasp, f16* __restrict__ xw)
{
    const int tid = threadIdx.x;
    const int w = tid >> 6, l = tid & 63;
    const int lr = l & 15, lq = l >> 4;
    const int n0 = blockIdx.x * 128;
    const int m0 = blockIdx.y * 128;

    f32x4 acc[2][8];
#pragma unroll
    for (int mt = 0; mt < 2; mt++)
#pragma unroll
        for (int nt = 0; nt < 8; nt++) acc[mt][nt] = (f32x4){0.f, 0.f, 0.f, 0.f};

    const float* a0 = A + (size_t)(m0 + 32 * w + lr) * 1024 + lq * 8;
    const f16x8* bp = (const f16x8*)Bp + (size_t)(n0 >> 4) * (32 * 64) + l;

#pragma unroll 2
    for (int s = 0; s < 32; s++) {
        f16x8 af[2];
#pragma unroll
        for (int mt = 0; mt < 2; mt++) {
            const float* ap = a0 + mt * (16 * 1024) + 32 * s;
            float4 v0 = *(const float4*)ap;
            float4 v1 = *(const float4*)(ap + 4);
            f16x8 tt;
            tt[0] = (f16)v0.x; tt[1] = (f16)v0.y; tt[2] = (f16)v0.z; tt[3] = (f16)v0.w;
            tt[4] = (f16)v1.x; tt[5] = (f16)v1.y; tt[6] = (f16)v1.z; tt[7] = (f16)v1.w;
            af[mt] = tt;
        }
#pragma unroll
        for (int nt = 0; nt < 8; nt++) {
            f16x8 bfr = bp[(size_t)(nt * 32 + s) * 64];
            acc[0][nt] = __builtin_amdgcn_mfma_f32_16x16x32_f16(af[0], bfr, acc[0][nt], 0, 0, 0);
            acc[1][nt] = __builtin_amdgcn_mfma_f32_16x16x32_f16(af[1], bfr, acc[1][nt], 0, 0, 0);
        }
    }
#pragma unroll
    for (int nt = 0; nt < 8; nt++) {
        int n = n0 + nt * 16 + lr;
        float bias = biasp[n];
#pragma unroll
        for (int mt = 0; mt < 2; mt++) {
#pragma unroll
            for (int r = 0; r < 4; r++) {
                int m = m0 + 32 * w + mt * 16 + lq * 4 + r;
                xw[(size_t)m * NTOT + n] = (f16)(acc[mt][nt][r] + bias);
            }
        }
    }
}

// ---------------------------------------------------------------------------
// Phase 2: persistent recurrent kernel, batch-grouped. 256 WGs x 256 thr.
// Group g = blockIdx&3 (16 batch rows), member j2 = blockIdx>>2 (64 gate cols).
// Weights: 128 KB dynamic LDS (4 n-tiles). Wave nt computes the 16-row tile x
// gate cols [16nt,+16) over k=1024 (32 MFMAs). Activation: tid<64, thread
// (b_local=tid>>2, q=tid&3) owns h cols 16*j2+4q..+4 -> ONE coherent u64 store
// into the next virgin ring slot (no fence needed anywhere).
// Barrier (per group, RMW-free): tid0 coherent-stores its flag line; wave 0
// polls the group's 64 flags in parallel (lane l watches member l) via __all.
// ---------------------------------------------------------------------------
__global__ __launch_bounds__(256, 1) void lstm_persist_ring(
    const f16* __restrict__ xw, const f16* __restrict__ whp,
    const int* __restrict__ lengths, const float* __restrict__ c0,
    float* __restrict__ out, f16* ring, unsigned int* flags)
{
    extern __shared__ __align__(16) char smem[];
    f16*   wlds    = (f16*)smem;                  // 128 KB weight fragments (4 n-tiles)
    float* pre_lds = (float*)(smem + 131072);     // 16 x 68 f32

    const int g  = blockIdx.x & 3;
    const int j2 = blockIdx.x >> 2;
    const int tid = threadIdx.x;
    const int wv = tid >> 6, l = tid & 63;
    const int lr = l & 15, lq = l >> 4;

    // stage this WG's 128 KB of recurrent-weight fragments (n-tiles 4*j2..+4)
    {
        const f16x8* wp = (const f16x8*)whp + (size_t)(4 * j2) * 2048;
        f16x8* wl0 = (f16x8*)wlds;
        for (int i = tid; i < 8192; i += 256) wl0[i] = wp[i];
    }
    __syncthreads();

    const int koff = lq * 8;
    const f16x8* wl = (const f16x8*)wlds + wv * 2048 + l;   // wave wv's n-tile; + s*64 per slice

    unsigned int* myflag = flags + (unsigned int)g * 1024u + (unsigned int)j2 * 16u;
    unsigned int* gflags = flags + (unsigned int)g * 1024u;

    // activation mapping (tid < 64): thread (b_local, q) owns h cols 16*j2+4q..+4
    const int b_local = tid >> 2, q = tid & 3;
    const int b_glob  = 16 * g + b_local;
    float cA = 0.f, cB = 0.f, cC = 0.f, cD = 0.f;
    int len = 0;
    const f16* xwbase = nullptr;
    f16x8 xg0 = (f16x8)0, xg1 = (f16x8)0;
    if (tid < 64) {
        float4 ci = *(const float4*)&c0[16 * j2 + 4 * q];
        cA = ci.x; cB = ci.y; cC = ci.z; cD = ci.w;
        len = lengths[b_glob];
        xwbase = xw + (size_t)b_glob * NTOT + 64 * j2 + 16 * q;   // 16 gate cols window
        xg0 = *(const f16x8*)xwbase;                              // step-0 x-contribution
        xg1 = *(const f16x8*)(xwbase + 8);
    }

    const size_t slab = (size_t)g * GSLAB_H;

    for (int t = 0; t < T_STEPS; t++) {
        const f16* hb = ring + (size_t)t * RSTRIDE_H + slab;     // virgin slot, this group's 16 rows
        const f16x8* ap = (const f16x8*)(hb + (size_t)lr * DD + koff);  // + s*4 per slice

        // prefetch next step's xw slice (read-only phase-1 data)
        f16x8 xg0n = xg0, xg1n = xg1;
        if (tid < 64 && t + 1 < T_STEPS) {
            const f16* nx = xwbase + (size_t)(t + 1) * (BATCH * NTOT);
            xg0n = *(const f16x8*)nx;
            xg1n = *(const f16x8*)(nx + 8);
        }

        f32x4 acc0 = {0.f, 0.f, 0.f, 0.f}, acc1 = {0.f, 0.f, 0.f, 0.f};
#pragma unroll
        for (int s = 0; s < 32; s += 2) {
            f16x8 a0 = ap[4 * s];
            f16x8 a1 = ap[4 * (s + 1)];
            f16x8 w0 = wl[64 * s];
            f16x8 w1 = wl[64 * (s + 1)];
            acc0 = __builtin_amdgcn_mfma_f32_16x16x32_f16(a0, w0, acc0, 0, 0, 0);
            acc1 = __builtin_amdgcn_mfma_f32_16x16x32_f16(a1, w1, acc1, 0, 0, 0);
        }
        f32x4 pre = acc0 + acc1;
        // D layout: row = lq*4 + r (batch local), col = 16*wv + lr (gate col local)
#pragma unroll
        for (int r = 0; r < 4; r++)
            pre_lds[(lq * 4 + r) * 68 + 16 * wv + lr] = pre[r];
        __syncthreads();

        float4 oh = (float4){0.f, 0.f, 0.f, 0.f};
        if (tid < 64) {
            const float* pr = &pre_lds[b_local * 68 + 16 * q];
            float4 g0 = *(const float4*)(pr + 0);
            float4 g1 = *(const float4*)(pr + 4);
            float4 g2 = *(const float4*)(pr + 8);
            float4 g3 = *(const float4*)(pr + 12);
            float h0, h1, h2, h3;
            GATE4(g0, xg0[0], xg0[1], xg0[2], xg0[3], cA, h0);
            GATE4(g1, xg0[4], xg0[5], xg0[6], xg0[7], cB, h1);
            GATE4(g2, xg1[0], xg1[1], xg1[2], xg1[3], cC, h2);
            GATE4(g3, xg1[4], xg1[5], xg1[6], xg1[7], cD, h3);
            if (t >= len) { h0 = 0.f; h1 = 0.f; h2 = 0.f; h3 = 0.f; }  // ref: mask carried+emitted
            oh = (float4){h0, h1, h2, h3};
            if (t + 1 < T_STEPS) {
                f16x4 hv;
                hv[0] = (f16)h0; hv[1] = (f16)h1; hv[2] = (f16)h2; hv[3] = (f16)h3;
                store_coh_u64((unsigned long long*)(ring + (size_t)(t + 1) * RSTRIDE_H + slab
                                                    + (size_t)b_local * DD + 16 * j2 + 4 * q),
                              __builtin_bit_cast(unsigned long long, hv));
            }
        }

        if (t + 1 < T_STEPS) {
            waitcnt_vm0();                    // h stores acked at coherency point
            __syncthreads();                  // whole WG done storing
            if (tid == 0) store_coh_u32(myflag, (unsigned int)(t + 1));
            // out store off the critical path (overlaps the poll)
            if (tid < 64)
                *(float4*)(out + (size_t)t * (BATCH * DD) + (size_t)b_glob * DD
                           + 16 * j2 + 4 * q) = oh;
            if (wv == 0) {                    // wave-parallel poll: lane l watches member l
                const unsigned int want = (unsigned int)(t + 1);
                while (!__all(load_coh_u32(gflags + 16 * l) >= want))
                    __builtin_amdgcn_s_sleep(1);
            }
            __syncthreads();                  // all waves ordered after observation
            // NO fence: next step reads a virgin ring slot (cannot be stale-cached)
            asm volatile("" ::: "memory");
        } else {
            if (tid < 64)
                *(float4*)(out + (size_t)t * (BATCH * DD) + (size_t)b_glob * DD
                           + 16 * j2 + 4 * q) = oh;
        }
        xg0 = xg0n; xg1 = xg1n;
    }
}

// ---------------------------------------------------------------------------
extern "C" void kernel_launch(void* const* d_in, const int* in_sizes, int n_in,
                              void* d_out, int out_size, void* d_ws, size_t ws_size,
                              hipStream_t stream) {
    const float* batch   = (const float*)d_in[0];
    const int*   lengths = (const int*)d_in[1];
    const float* c0      = (const float*)d_in[2];
    const float* Wi = (const float*)d_in[3];
    const float* bi = (const float*)d_in[4];
    const float* Wf = (const float*)d_in[5];
    const float* bf = (const float*)d_in[6];
    const float* Wc = (const float*)d_in[7];
    const float* bc = (const float*)d_in[8];
    const float* Wo = (const float*)d_in[9];
    const float* bo = (const float*)d_in[10];
    float* out = (float*)d_out;

    char* ws = (char*)d_ws;
    unsigned int* flags = (unsigned int*)(ws + OFF_FLAGS);
    float* biasp = (float*)(ws + OFF_BIAS);
    f16*   whp   = (f16*)(ws + OFF_WHP);
    f16*   bxp   = (f16*)(ws + OFF_BXP);
    f16*   xw    = (f16*)(ws + OFF_XW);
    f16*   ring  = (f16*)(ws + OFF_RING);

    prepack_kernel<<<33040, 256, 0, stream>>>(Wi, Wf, Wc, Wo, bi, bf, bc, bo, c0,
                                              whp, bxp, biasp, ring, flags);
    gemm_x_kernel<<<dim3(32, 256), 256, 0, stream>>>(batch, bxp, biasp, xw);
    // dynamic LDS: 128 KB weights + 16*68*4 B pre = 135424 B (<160 KB/CU)
    lstm_persist_ring<<<256, 256, 135424, stream>>>(xw, whp, lengths, c0, out, ring, flags);
}